// Round 1
// baseline (2225.903 us; speedup 1.0000x reference)
//
#include <hip/hip_runtime.h>

#define NUM_USERS 50000
#define NUM_ITEMS 50000
#define N_NODES   100000
#define NNZ       3200000
#define EMB_DIM   64
#define N_LAYERS  3
#define BATCH     16384

// init: bufA = acc = concat(user_emb, item_emb), vectorized float4
__global__ void init_emb_kernel(const float* __restrict__ ue,
                                const float* __restrict__ ie,
                                float* __restrict__ bufA,
                                float* __restrict__ acc) {
    int idx = blockIdx.x * blockDim.x + threadIdx.x;   // over N_NODES*16 float4s
    const int total = N_NODES * (EMB_DIM / 4);
    if (idx >= total) return;
    const int uoff = NUM_USERS * (EMB_DIM / 4);
    float4 v;
    if (idx < uoff) v = ((const float4*)ue)[idx];
    else            v = ((const float4*)ie)[idx - uoff];
    ((float4*)bufA)[idx] = v;
    ((float4*)acc)[idx]  = v;
}

// scatter: one lane per (edge, dim). 64 consecutive lanes = one edge -> the
// 64 atomicAdds per edge hit 64 consecutive floats (coalesced cache lines).
__global__ void scatter_kernel(const float* __restrict__ A,
                               float* __restrict__ B,
                               const float* __restrict__ ev,
                               const int*  __restrict__ es,
                               const int*  __restrict__ ed) {
    long long t = (long long)blockIdx.x * blockDim.x + threadIdx.x;
    int e = (int)(t >> 6);
    int d = (int)(t & 63);
    if (e >= NNZ) return;
    float val = ev[e];
    int   s   = es[e];
    int   dst = ed[e];
    atomicAdd(&B[(long long)dst * EMB_DIM + d], val * A[(long long)s * EMB_DIM + d]);
}

// acc += B (float4)
__global__ void accum_kernel(float* __restrict__ acc, const float* __restrict__ B) {
    int idx = blockIdx.x * blockDim.x + threadIdx.x;
    const int total = N_NODES * (EMB_DIM / 4);
    if (idx >= total) return;
    float4 a = ((float4*)acc)[idx];
    float4 b = ((const float4*)B)[idx];
    a.x += b.x; a.y += b.y; a.z += b.z; a.w += b.w;
    ((float4*)acc)[idx] = a;
}

// one wave (64 lanes) per batch element: dot(acc[u], acc[NUM_USERS+i]) / 16
__global__ void dot_kernel(const float* __restrict__ acc,
                           const int* __restrict__ users,
                           const int* __restrict__ items,
                           float* __restrict__ out) {
    int t = blockIdx.x * blockDim.x + threadIdx.x;
    int b = t >> 6;
    int d = t & 63;
    if (b >= BATCH) return;
    int u  = users[b];
    int it = items[b] + NUM_USERS;
    float p = acc[(long long)u * EMB_DIM + d] * acc[(long long)it * EMB_DIM + d];
    #pragma unroll
    for (int off = 32; off >= 1; off >>= 1)
        p += __shfl_down(p, off, 64);
    if (d == 0) out[b] = p * 0.0625f;   // (1/4)*(1/4) layer-mean factors
}

extern "C" void kernel_launch(void* const* d_in, const int* in_sizes, int n_in,
                              void* d_out, int out_size, void* d_ws, size_t ws_size,
                              hipStream_t stream) {
    const float* user_emb = (const float*)d_in[0];
    const float* item_emb = (const float*)d_in[1];
    const float* edge_val = (const float*)d_in[2];
    const int*   edge_src = (const int*)d_in[3];
    const int*   edge_dst = (const int*)d_in[4];
    const int*   users    = (const int*)d_in[5];
    const int*   items    = (const int*)d_in[6];
    float* out = (float*)d_out;

    const size_t embBytes = (size_t)N_NODES * EMB_DIM * sizeof(float); // 25.6 MB
    float* bufA = (float*)d_ws;
    float* bufB = (float*)((char*)d_ws + embBytes);
    float* acc  = (float*)((char*)d_ws + 2 * embBytes);

    const int vecTotal = N_NODES * (EMB_DIM / 4);
    const int initBlocks = (vecTotal + 255) / 256;

    init_emb_kernel<<<initBlocks, 256, 0, stream>>>(user_emb, item_emb, bufA, acc);

    const long long scatterThreads = (long long)NNZ * 64;
    const int scatterBlocks = (int)((scatterThreads + 255) / 256);

    for (int layer = 0; layer < N_LAYERS; ++layer) {
        hipMemsetAsync(bufB, 0, embBytes, stream);
        scatter_kernel<<<scatterBlocks, 256, 0, stream>>>(bufA, bufB, edge_val, edge_src, edge_dst);
        accum_kernel<<<initBlocks, 256, 0, stream>>>(acc, bufB);
        float* tmp = bufA; bufA = bufB; bufB = tmp;
    }

    const int dotBlocks = (BATCH * 64 + 255) / 256;
    dot_kernel<<<dotBlocks, 256, 0, stream>>>(acc, users, items, out);
}

// Round 2
// 1329.683 us; speedup vs baseline: 1.6740x; 1.6740x over previous
//
#include <hip/hip_runtime.h>

#define NUM_USERS 50000
#define NUM_ITEMS 50000
#define N_NODES   100000
#define NNZ       3200000
#define EMB_DIM   64
#define N_LAYERS  3
#define BATCH     16384

#define SCAN_BS 256
#define NB ((N_NODES + SCAN_BS - 1) / SCAN_BS)   // 391

// init: bufA = acc = concat(user_emb, item_emb), vectorized float4
__global__ void init_emb_kernel(const float* __restrict__ ue,
                                const float* __restrict__ ie,
                                float* __restrict__ bufA,
                                float* __restrict__ acc) {
    int idx = blockIdx.x * blockDim.x + threadIdx.x;
    const int total = N_NODES * (EMB_DIM / 4);
    if (idx >= total) return;
    const int uoff = NUM_USERS * (EMB_DIM / 4);
    float4 v;
    if (idx < uoff) v = ((const float4*)ue)[idx];
    else            v = ((const float4*)ie)[idx - uoff];
    ((float4*)bufA)[idx] = v;
    ((float4*)acc)[idx]  = v;
}

// ---- counting sort of edges by dst ----

__global__ void hist_kernel(const int* __restrict__ ed, int* __restrict__ deg) {
    int e = blockIdx.x * blockDim.x + threadIdx.x;
    if (e >= NNZ) return;
    atomicAdd(&deg[ed[e]], 1);
}

// per-block exclusive scan (Hillis-Steele in LDS) + block totals
__global__ void scan1_kernel(const int* __restrict__ deg,
                             int* __restrict__ partial,
                             int* __restrict__ blockSums) {
    __shared__ int sm[SCAN_BS];
    int t = threadIdx.x;
    int g = blockIdx.x * SCAN_BS + t;
    int v = (g < N_NODES) ? deg[g] : 0;
    sm[t] = v;
    __syncthreads();
    for (int off = 1; off < SCAN_BS; off <<= 1) {
        int add = (t >= off) ? sm[t - off] : 0;
        __syncthreads();
        sm[t] += add;
        __syncthreads();
    }
    int inclusive = sm[t];
    if (g < N_NODES) partial[g] = inclusive - v;     // exclusive within block
    if (t == SCAN_BS - 1) blockSums[blockIdx.x] = inclusive;
}

// single-block exclusive scan of the 391 block sums (512 threads)
__global__ void scan2_kernel(const int* __restrict__ blockSums,
                             int* __restrict__ blockScanned) {
    __shared__ int sm[512];
    int t = threadIdx.x;
    int v = (t < NB) ? blockSums[t] : 0;
    sm[t] = v;
    __syncthreads();
    for (int off = 1; off < 512; off <<= 1) {
        int add = (t >= off) ? sm[t - off] : 0;
        __syncthreads();
        sm[t] += add;
        __syncthreads();
    }
    if (t < NB) blockScanned[t] = sm[t] - v;         // exclusive
}

__global__ void scan3_kernel(const int* __restrict__ partial,
                             const int* __restrict__ blockScanned,
                             int* __restrict__ rowStart,
                             int* __restrict__ cursor) {
    int g = blockIdx.x * blockDim.x + threadIdx.x;
    if (g >= N_NODES) return;
    int rs = partial[g] + blockScanned[g >> 8];      // SCAN_BS == 256
    rowStart[g] = rs;
    cursor[g]   = rs;
}

__global__ void place_kernel(const float* __restrict__ ev,
                             const int*  __restrict__ es,
                             const int*  __restrict__ ed,
                             int* __restrict__ cursor,
                             int2* __restrict__ sorted) {
    int e = blockIdx.x * blockDim.x + threadIdx.x;
    if (e >= NNZ) return;
    int dst = ed[e];
    int pos = atomicAdd(&cursor[dst], 1);
    sorted[pos] = make_int2(es[e], __float_as_int(ev[e]));
}

// ---- pull propagation: one wave per dst node, lane = dim ----
// B[node] = sum_j val_j * A[src_j];  acc[node] += B[node]
__global__ void pull_kernel(const float* __restrict__ A,
                            float* __restrict__ B,
                            float* __restrict__ acc,
                            const int2* __restrict__ sorted,
                            const int* __restrict__ rowStart,
                            const int* __restrict__ deg) {
    int t = blockIdx.x * blockDim.x + threadIdx.x;
    int node = t >> 6;
    int d = t & 63;
    if (node >= N_NODES) return;
    int start = rowStart[node];
    int cnt   = deg[node];
    float s = 0.f;
    for (int j = 0; j < cnt; ++j) {
        int2 e = sorted[start + j];                  // wave-uniform broadcast load
        s += __int_as_float(e.y) * A[((long long)e.x << 6) + d];
    }
    long long o = ((long long)node << 6) + d;
    B[o] = s;
    acc[o] += s;
}

// one wave per batch element: dot(acc[u], acc[NUM_USERS+i]) / 16
__global__ void dot_kernel(const float* __restrict__ acc,
                           const int* __restrict__ users,
                           const int* __restrict__ items,
                           float* __restrict__ out) {
    int t = blockIdx.x * blockDim.x + threadIdx.x;
    int b = t >> 6;
    int d = t & 63;
    if (b >= BATCH) return;
    int u  = users[b];
    int it = items[b] + NUM_USERS;
    float p = acc[(long long)u * EMB_DIM + d] * acc[(long long)it * EMB_DIM + d];
    #pragma unroll
    for (int off = 32; off >= 1; off >>= 1)
        p += __shfl_down(p, off, 64);
    if (d == 0) out[b] = p * 0.0625f;
}

extern "C" void kernel_launch(void* const* d_in, const int* in_sizes, int n_in,
                              void* d_out, int out_size, void* d_ws, size_t ws_size,
                              hipStream_t stream) {
    const float* user_emb = (const float*)d_in[0];
    const float* item_emb = (const float*)d_in[1];
    const float* edge_val = (const float*)d_in[2];
    const int*   edge_src = (const int*)d_in[3];
    const int*   edge_dst = (const int*)d_in[4];
    const int*   users    = (const int*)d_in[5];
    const int*   items    = (const int*)d_in[6];
    float* out = (float*)d_out;

    const size_t embBytes  = (size_t)N_NODES * EMB_DIM * sizeof(float);  // 25.6 MB
    const size_t edgeBytes = (size_t)NNZ * sizeof(int2);                 // 25.6 MB
    const size_t nodeBytes = (size_t)N_NODES * sizeof(int);              // 400 KB

    char* w = (char*)d_ws;
    float* bufA       = (float*)(w);                    w += embBytes;
    float* bufB       = (float*)(w);                    w += embBytes;
    float* acc        = (float*)(w);                    w += embBytes;
    int2*  sorted     = (int2*)(w);                     w += edgeBytes;
    int*   deg        = (int*)(w);                      w += nodeBytes;
    int*   partial    = (int*)(w);                      w += nodeBytes;
    int*   rowStart   = (int*)(w);                      w += nodeBytes;
    int*   cursor     = (int*)(w);                      w += nodeBytes;
    int*   blockSums  = (int*)(w);                      w += 512 * sizeof(int);
    int*   blockScan  = (int*)(w);                      w += 512 * sizeof(int);

    const int vecTotal   = N_NODES * (EMB_DIM / 4);
    const int initBlocks = (vecTotal + 255) / 256;
    const int edgeBlocks = (NNZ + 255) / 256;
    const int nodeBlocks = (N_NODES + 255) / 256;

    init_emb_kernel<<<initBlocks, 256, 0, stream>>>(user_emb, item_emb, bufA, acc);

    // counting sort by dst
    hipMemsetAsync(deg, 0, nodeBytes, stream);
    hist_kernel<<<edgeBlocks, 256, 0, stream>>>(edge_dst, deg);
    scan1_kernel<<<NB, SCAN_BS, 0, stream>>>(deg, partial, blockSums);
    scan2_kernel<<<1, 512, 0, stream>>>(blockSums, blockScan);
    scan3_kernel<<<nodeBlocks, 256, 0, stream>>>(partial, blockScan, rowStart, cursor);
    place_kernel<<<edgeBlocks, 256, 0, stream>>>(edge_val, edge_src, edge_dst, cursor, sorted);

    // 3 pull layers, acc fused
    const int pullBlocks = (N_NODES * 64 + 255) / 256;
    for (int layer = 0; layer < N_LAYERS; ++layer) {
        pull_kernel<<<pullBlocks, 256, 0, stream>>>(bufA, bufB, acc, sorted, rowStart, deg);
        float* tmp = bufA; bufA = bufB; bufB = tmp;
    }

    const int dotBlocks = (BATCH * 64 + 255) / 256;
    dot_kernel<<<dotBlocks, 256, 0, stream>>>(acc, users, items, out);
}

// Round 3
// 823.059 us; speedup vs baseline: 2.7044x; 1.6155x over previous
//
#include <hip/hip_runtime.h>

#define NUM_USERS 50000
#define NUM_ITEMS 50000
#define N_NODES   100000
#define NNZ       3200000
#define EMB_DIM   64
#define N_LAYERS  3
#define BATCH     16384

#define SCAN_BS 256
#define NB ((N_NODES + SCAN_BS - 1) / SCAN_BS)   // 391

// init: bufA = acc = concat(user_emb, item_emb), vectorized float4
__global__ void init_emb_kernel(const float* __restrict__ ue,
                                const float* __restrict__ ie,
                                float* __restrict__ bufA,
                                float* __restrict__ acc) {
    int idx = blockIdx.x * blockDim.x + threadIdx.x;
    const int total = N_NODES * (EMB_DIM / 4);
    if (idx >= total) return;
    const int uoff = NUM_USERS * (EMB_DIM / 4);
    float4 v;
    if (idx < uoff) v = ((const float4*)ue)[idx];
    else            v = ((const float4*)ie)[idx - uoff];
    ((float4*)bufA)[idx] = v;
    ((float4*)acc)[idx]  = v;
}

// ---- counting sort of edges by dst ----

__global__ void hist_kernel(const int* __restrict__ ed, int* __restrict__ deg) {
    int e = blockIdx.x * blockDim.x + threadIdx.x;
    if (e >= NNZ) return;
    atomicAdd(&deg[ed[e]], 1);
}

__global__ void scan1_kernel(const int* __restrict__ deg,
                             int* __restrict__ partial,
                             int* __restrict__ blockSums) {
    __shared__ int sm[SCAN_BS];
    int t = threadIdx.x;
    int g = blockIdx.x * SCAN_BS + t;
    int v = (g < N_NODES) ? deg[g] : 0;
    sm[t] = v;
    __syncthreads();
    for (int off = 1; off < SCAN_BS; off <<= 1) {
        int add = (t >= off) ? sm[t - off] : 0;
        __syncthreads();
        sm[t] += add;
        __syncthreads();
    }
    int inclusive = sm[t];
    if (g < N_NODES) partial[g] = inclusive - v;
    if (t == SCAN_BS - 1) blockSums[blockIdx.x] = inclusive;
}

__global__ void scan2_kernel(const int* __restrict__ blockSums,
                             int* __restrict__ blockScanned) {
    __shared__ int sm[512];
    int t = threadIdx.x;
    int v = (t < NB) ? blockSums[t] : 0;
    sm[t] = v;
    __syncthreads();
    for (int off = 1; off < 512; off <<= 1) {
        int add = (t >= off) ? sm[t - off] : 0;
        __syncthreads();
        sm[t] += add;
        __syncthreads();
    }
    if (t < NB) blockScanned[t] = sm[t] - v;
}

__global__ void scan3_kernel(const int* __restrict__ partial,
                             const int* __restrict__ blockScanned,
                             int* __restrict__ rowStart,
                             int* __restrict__ cursor) {
    int g = blockIdx.x * blockDim.x + threadIdx.x;
    if (g >= N_NODES) return;
    int rs = partial[g] + blockScanned[g >> 8];
    rowStart[g] = rs;
    cursor[g]   = rs;
}

__global__ void place_kernel(const float* __restrict__ ev,
                             const int*  __restrict__ es,
                             const int*  __restrict__ ed,
                             int* __restrict__ cursor,
                             int2* __restrict__ sorted) {
    int e = blockIdx.x * blockDim.x + threadIdx.x;
    if (e >= NNZ) return;
    int dst = ed[e];
    int pos = atomicAdd(&cursor[dst], 1);
    sorted[pos] = make_int2(es[e], __float_as_int(ev[e]));
}

// ---- pull propagation: one wave per dst node, lane = dim ----
// Unroll x8 with 8 accumulators + software-pipelined edge prefetch:
// 8 independent gathers in flight per wave (latency -> throughput).
__global__ void pull_kernel(const float* __restrict__ A,
                            float* __restrict__ B,
                            float* __restrict__ acc,
                            const int2* __restrict__ sorted,
                            const int* __restrict__ rowStart,
                            const int* __restrict__ deg,
                            int writeB) {
    int t = blockIdx.x * blockDim.x + threadIdx.x;
    int node = t >> 6;
    int d = t & 63;
    if (node >= N_NODES) return;
    int start = rowStart[node];
    int cnt   = deg[node];            // wave-uniform
    const int2* ep = sorted + start;

    float s0=0.f,s1=0.f,s2=0.f,s3=0.f,s4=0.f,s5=0.f,s6=0.f,s7=0.f;
    int j = 0;
    if (cnt >= 8) {
        int2 e0=ep[0],e1=ep[1],e2=ep[2],e3=ep[3],e4=ep[4],e5=ep[5],e6=ep[6],e7=ep[7];
        for (;;) {
            // 8 independent gathers issue back-to-back
            float a0 = A[(((long long)e0.x) << 6) + d];
            float a1 = A[(((long long)e1.x) << 6) + d];
            float a2 = A[(((long long)e2.x) << 6) + d];
            float a3 = A[(((long long)e3.x) << 6) + d];
            float a4 = A[(((long long)e4.x) << 6) + d];
            float a5 = A[(((long long)e5.x) << 6) + d];
            float a6 = A[(((long long)e6.x) << 6) + d];
            float a7 = A[(((long long)e7.x) << 6) + d];
            int nj = j + 8;
            bool more = (nj + 8 <= cnt);          // wave-uniform branch
            int2 f0,f1,f2,f3,f4,f5,f6,f7;
            if (more) {                           // prefetch next group while gathers land
                f0=ep[nj];  f1=ep[nj+1]; f2=ep[nj+2]; f3=ep[nj+3];
                f4=ep[nj+4];f5=ep[nj+5]; f6=ep[nj+6]; f7=ep[nj+7];
            }
            s0 = fmaf(__int_as_float(e0.y), a0, s0);
            s1 = fmaf(__int_as_float(e1.y), a1, s1);
            s2 = fmaf(__int_as_float(e2.y), a2, s2);
            s3 = fmaf(__int_as_float(e3.y), a3, s3);
            s4 = fmaf(__int_as_float(e4.y), a4, s4);
            s5 = fmaf(__int_as_float(e5.y), a5, s5);
            s6 = fmaf(__int_as_float(e6.y), a6, s6);
            s7 = fmaf(__int_as_float(e7.y), a7, s7);
            j = nj;
            if (!more) break;
            e0=f0; e1=f1; e2=f2; e3=f3; e4=f4; e5=f5; e6=f6; e7=f7;
        }
    }
    for (; j < cnt; ++j) {
        int2 e = ep[j];
        s0 = fmaf(__int_as_float(e.y), A[(((long long)e.x) << 6) + d], s0);
    }
    float s = ((s0+s1)+(s2+s3)) + ((s4+s5)+(s6+s7));

    long long o = ((long long)node << 6) + d;
    if (writeB) B[o] = s;
    acc[o] += s;
}

// one wave per batch element: dot(acc[u], acc[NUM_USERS+i]) / 16
__global__ void dot_kernel(const float* __restrict__ acc,
                           const int* __restrict__ users,
                           const int* __restrict__ items,
                           float* __restrict__ out) {
    int t = blockIdx.x * blockDim.x + threadIdx.x;
    int b = t >> 6;
    int d = t & 63;
    if (b >= BATCH) return;
    int u  = users[b];
    int it = items[b] + NUM_USERS;
    float p = acc[(long long)u * EMB_DIM + d] * acc[(long long)it * EMB_DIM + d];
    #pragma unroll
    for (int off = 32; off >= 1; off >>= 1)
        p += __shfl_down(p, off, 64);
    if (d == 0) out[b] = p * 0.0625f;
}

extern "C" void kernel_launch(void* const* d_in, const int* in_sizes, int n_in,
                              void* d_out, int out_size, void* d_ws, size_t ws_size,
                              hipStream_t stream) {
    const float* user_emb = (const float*)d_in[0];
    const float* item_emb = (const float*)d_in[1];
    const float* edge_val = (const float*)d_in[2];
    const int*   edge_src = (const int*)d_in[3];
    const int*   edge_dst = (const int*)d_in[4];
    const int*   users    = (const int*)d_in[5];
    const int*   items    = (const int*)d_in[6];
    float* out = (float*)d_out;

    const size_t embBytes  = (size_t)N_NODES * EMB_DIM * sizeof(float);  // 25.6 MB
    const size_t edgeBytes = (size_t)NNZ * sizeof(int2);                 // 25.6 MB
    const size_t nodeBytes = (size_t)N_NODES * sizeof(int);              // 400 KB

    char* w = (char*)d_ws;
    float* bufA       = (float*)(w);                    w += embBytes;
    float* bufB       = (float*)(w);                    w += embBytes;
    float* acc        = (float*)(w);                    w += embBytes;
    int2*  sorted     = (int2*)(w);                     w += edgeBytes;
    int*   deg        = (int*)(w);                      w += nodeBytes;
    int*   partial    = (int*)(w);                      w += nodeBytes;
    int*   rowStart   = (int*)(w);                      w += nodeBytes;
    int*   cursor     = (int*)(w);                      w += nodeBytes;
    int*   blockSums  = (int*)(w);                      w += 512 * sizeof(int);
    int*   blockScan  = (int*)(w);                      w += 512 * sizeof(int);

    const int vecTotal   = N_NODES * (EMB_DIM / 4);
    const int initBlocks = (vecTotal + 255) / 256;
    const int edgeBlocks = (NNZ + 255) / 256;
    const int nodeBlocks = (N_NODES + 255) / 256;

    init_emb_kernel<<<initBlocks, 256, 0, stream>>>(user_emb, item_emb, bufA, acc);

    hipMemsetAsync(deg, 0, nodeBytes, stream);
    hist_kernel<<<edgeBlocks, 256, 0, stream>>>(edge_dst, deg);
    scan1_kernel<<<NB, SCAN_BS, 0, stream>>>(deg, partial, blockSums);
    scan2_kernel<<<1, 512, 0, stream>>>(blockSums, blockScan);
    scan3_kernel<<<nodeBlocks, 256, 0, stream>>>(partial, blockScan, rowStart, cursor);
    place_kernel<<<edgeBlocks, 256, 0, stream>>>(edge_val, edge_src, edge_dst, cursor, sorted);

    const int pullBlocks = (N_NODES * 64 + 255) / 256;
    for (int layer = 0; layer < N_LAYERS; ++layer) {
        pull_kernel<<<pullBlocks, 256, 0, stream>>>(bufA, bufB, acc, sorted, rowStart, deg,
                                                    layer < N_LAYERS - 1 ? 1 : 0);
        float* tmp = bufA; bufA = bufB; bufB = tmp;
    }

    const int dotBlocks = (BATCH * 64 + 255) / 256;
    dot_kernel<<<dotBlocks, 256, 0, stream>>>(acc, users, items, out);
}

// Round 4
// 716.173 us; speedup vs baseline: 3.1081x; 1.1492x over previous
//
#include <hip/hip_runtime.h>

#define NUM_USERS 50000
#define NUM_ITEMS 50000
#define N_NODES   100000
#define NNZ       3200000
#define EMB_DIM   64
#define N_LAYERS  3
#define BATCH     16384

#define SCAN_BS 256
#define NB ((N_NODES + SCAN_BS - 1) / SCAN_BS)   // 391

#define NBUCK 256
#define ABITS 9                 // bucket = dst >> 9 (512 nodes/bucket, 196 used)
#define TILE_EDGES 8192

// init: bufA = acc = concat(user_emb, item_emb), vectorized float4
__global__ void init_emb_kernel(const float* __restrict__ ue,
                                const float* __restrict__ ie,
                                float* __restrict__ bufA,
                                float* __restrict__ acc) {
    int idx = blockIdx.x * blockDim.x + threadIdx.x;
    const int total = N_NODES * (EMB_DIM / 4);
    if (idx >= total) return;
    const int uoff = NUM_USERS * (EMB_DIM / 4);
    float4 v;
    if (idx < uoff) v = ((const float4*)ue)[idx];
    else            v = ((const float4*)ie)[idx - uoff];
    ((float4*)bufA)[idx] = v;
    ((float4*)acc)[idx]  = v;
}

// ---- CSR build: node-degree histogram + scan ----

__global__ void hist_kernel(const int* __restrict__ ed, int* __restrict__ deg) {
    int e = blockIdx.x * blockDim.x + threadIdx.x;
    if (e >= NNZ) return;
    atomicAdd(&deg[ed[e]], 1);
}

__global__ void scan1_kernel(const int* __restrict__ deg,
                             int* __restrict__ partial,
                             int* __restrict__ blockSums) {
    __shared__ int sm[SCAN_BS];
    int t = threadIdx.x;
    int g = blockIdx.x * SCAN_BS + t;
    int v = (g < N_NODES) ? deg[g] : 0;
    sm[t] = v;
    __syncthreads();
    for (int off = 1; off < SCAN_BS; off <<= 1) {
        int add = (t >= off) ? sm[t - off] : 0;
        __syncthreads();
        sm[t] += add;
        __syncthreads();
    }
    int inclusive = sm[t];
    if (g < N_NODES) partial[g] = inclusive - v;
    if (t == SCAN_BS - 1) blockSums[blockIdx.x] = inclusive;
}

__global__ void scan2_kernel(const int* __restrict__ blockSums,
                             int* __restrict__ blockScanned) {
    __shared__ int sm[512];
    int t = threadIdx.x;
    int v = (t < NB) ? blockSums[t] : 0;
    sm[t] = v;
    __syncthreads();
    for (int off = 1; off < 512; off <<= 1) {
        int add = (t >= off) ? sm[t - off] : 0;
        __syncthreads();
        sm[t] += add;
        __syncthreads();
    }
    if (t < NB) blockScanned[t] = sm[t] - v;
}

__global__ void scan3_kernel(const int* __restrict__ partial,
                             const int* __restrict__ blockScanned,
                             int* __restrict__ rowStart) {
    int g = blockIdx.x * blockDim.x + threadIdx.x;
    if (g >= N_NODES) return;
    rowStart[g] = partial[g] + blockScanned[g >> 8];
}

// bucket cursors: bucketStart[b] = rowStart[b << ABITS] (bucket == node range)
__global__ void bucket_init_kernel(const int* __restrict__ rowStart,
                                   int* __restrict__ bucketCursor) {
    int b = threadIdx.x;      // 256
    int node = b << ABITS;
    bucketCursor[b] = (node < N_NODES) ? rowStart[node] : NNZ;
}

// ---- pass A: partition edges into 256 coarse buckets (packed u64 records) ----
// rec = src(17) | dst(17)<<17 | (val_bits>>2)<<34   (drops 2 mantissa bits)
__global__ void partA_kernel(const float* __restrict__ ev,
                             const int*  __restrict__ es,
                             const int*  __restrict__ ed,
                             int* __restrict__ bucketCursor,
                             unsigned long long* __restrict__ tmp) {
    __shared__ int hist[NBUCK];
    __shared__ int base[NBUCK];
    __shared__ int cnt2[NBUCK];
    int tid = threadIdx.x;
    int e0 = blockIdx.x * TILE_EDGES;

    for (int i = tid; i < NBUCK; i += 256) hist[i] = 0;
    __syncthreads();

    for (int i = tid; i < TILE_EDGES; i += 256) {
        int e = e0 + i;
        if (e < NNZ) atomicAdd(&hist[ed[e] >> ABITS], 1);
    }
    __syncthreads();

    for (int i = tid; i < NBUCK; i += 256) {
        int c = hist[i];
        base[i] = c ? atomicAdd(&bucketCursor[i], c) : 0;
        cnt2[i] = 0;
    }
    __syncthreads();

    for (int i = tid; i < TILE_EDGES; i += 256) {
        int e = e0 + i;
        if (e >= NNZ) continue;
        int dst = ed[e];
        int b = dst >> ABITS;
        int pos = base[b] + atomicAdd(&cnt2[b], 1);
        unsigned long long rec =
            (unsigned long long)(unsigned)es[e]
          | ((unsigned long long)(unsigned)dst << 17)
          | ((unsigned long long)(((unsigned)__float_as_int(ev[e])) >> 2) << 34);
        tmp[pos] = rec;
    }
}

// ---- pass B: within-bucket scatter to final CSR position, cursors in LDS ----
__global__ void partB_kernel(const unsigned long long* __restrict__ tmp,
                             const int* __restrict__ rowStart,
                             int2* __restrict__ sorted) {
    __shared__ int cur[1 << ABITS];   // 512 node cursors
    int b = blockIdx.x;
    int nodeLo = b << ABITS;
    int tid = threadIdx.x;            // 1024 threads

    if (tid < (1 << ABITS)) {
        int node = nodeLo + tid;
        cur[tid] = (node < N_NODES) ? rowStart[node] : 0;
    }
    __syncthreads();

    int startE = rowStart[nodeLo];    // nodeLo < N_NODES for all launched b
    int endNode = nodeLo + (1 << ABITS);
    int endE = (endNode < N_NODES) ? rowStart[endNode] : NNZ;

    for (int i = startE + tid; i < endE; i += 1024) {
        unsigned long long rec = tmp[i];
        int src = (int)(rec & 0x1FFFFULL);
        int dst = (int)((rec >> 17) & 0x1FFFFULL);
        int vbits = (int)((rec >> 34) << 2);
        int pos = atomicAdd(&cur[dst - nodeLo], 1);
        sorted[pos] = make_int2(src, vbits);
    }
}

// ---- pull propagation: one wave per dst node, lane = dim, unroll x8 ----
__global__ void pull_kernel(const float* __restrict__ A,
                            float* __restrict__ B,
                            float* __restrict__ acc,
                            const int2* __restrict__ sorted,
                            const int* __restrict__ rowStart,
                            const int* __restrict__ deg,
                            int writeB) {
    int t = blockIdx.x * blockDim.x + threadIdx.x;
    int node = t >> 6;
    int d = t & 63;
    if (node >= N_NODES) return;
    int start = rowStart[node];
    int cnt   = deg[node];            // wave-uniform
    const int2* ep = sorted + start;

    float s0=0.f,s1=0.f,s2=0.f,s3=0.f,s4=0.f,s5=0.f,s6=0.f,s7=0.f;
    int j = 0;
    if (cnt >= 8) {
        int2 e0=ep[0],e1=ep[1],e2=ep[2],e3=ep[3],e4=ep[4],e5=ep[5],e6=ep[6],e7=ep[7];
        for (;;) {
            float a0 = A[(((long long)e0.x) << 6) + d];
            float a1 = A[(((long long)e1.x) << 6) + d];
            float a2 = A[(((long long)e2.x) << 6) + d];
            float a3 = A[(((long long)e3.x) << 6) + d];
            float a4 = A[(((long long)e4.x) << 6) + d];
            float a5 = A[(((long long)e5.x) << 6) + d];
            float a6 = A[(((long long)e6.x) << 6) + d];
            float a7 = A[(((long long)e7.x) << 6) + d];
            int nj = j + 8;
            bool more = (nj + 8 <= cnt);
            int2 f0,f1,f2,f3,f4,f5,f6,f7;
            if (more) {
                f0=ep[nj];  f1=ep[nj+1]; f2=ep[nj+2]; f3=ep[nj+3];
                f4=ep[nj+4];f5=ep[nj+5]; f6=ep[nj+6]; f7=ep[nj+7];
            }
            s0 = fmaf(__int_as_float(e0.y), a0, s0);
            s1 = fmaf(__int_as_float(e1.y), a1, s1);
            s2 = fmaf(__int_as_float(e2.y), a2, s2);
            s3 = fmaf(__int_as_float(e3.y), a3, s3);
            s4 = fmaf(__int_as_float(e4.y), a4, s4);
            s5 = fmaf(__int_as_float(e5.y), a5, s5);
            s6 = fmaf(__int_as_float(e6.y), a6, s6);
            s7 = fmaf(__int_as_float(e7.y), a7, s7);
            j = nj;
            if (!more) break;
            e0=f0; e1=f1; e2=f2; e3=f3; e4=f4; e5=f5; e6=f6; e7=f7;
        }
    }
    for (; j < cnt; ++j) {
        int2 e = ep[j];
        s0 = fmaf(__int_as_float(e.y), A[(((long long)e.x) << 6) + d], s0);
    }
    float s = ((s0+s1)+(s2+s3)) + ((s4+s5)+(s6+s7));

    long long o = ((long long)node << 6) + d;
    if (writeB) B[o] = s;
    acc[o] += s;
}

// one wave per batch element: dot(acc[u], acc[NUM_USERS+i]) / 16
__global__ void dot_kernel(const float* __restrict__ acc,
                           const int* __restrict__ users,
                           const int* __restrict__ items,
                           float* __restrict__ out) {
    int t = blockIdx.x * blockDim.x + threadIdx.x;
    int b = t >> 6;
    int d = t & 63;
    if (b >= BATCH) return;
    int u  = users[b];
    int it = items[b] + NUM_USERS;
    float p = acc[(long long)u * EMB_DIM + d] * acc[(long long)it * EMB_DIM + d];
    #pragma unroll
    for (int off = 32; off >= 1; off >>= 1)
        p += __shfl_down(p, off, 64);
    if (d == 0) out[b] = p * 0.0625f;
}

extern "C" void kernel_launch(void* const* d_in, const int* in_sizes, int n_in,
                              void* d_out, int out_size, void* d_ws, size_t ws_size,
                              hipStream_t stream) {
    const float* user_emb = (const float*)d_in[0];
    const float* item_emb = (const float*)d_in[1];
    const float* edge_val = (const float*)d_in[2];
    const int*   edge_src = (const int*)d_in[3];
    const int*   edge_dst = (const int*)d_in[4];
    const int*   users    = (const int*)d_in[5];
    const int*   items    = (const int*)d_in[6];
    float* out = (float*)d_out;

    const size_t embBytes  = (size_t)N_NODES * EMB_DIM * sizeof(float);  // 25.6 MB
    const size_t edgeBytes = (size_t)NNZ * sizeof(int2);                 // 25.6 MB
    const size_t nodeBytes = (size_t)N_NODES * sizeof(int);              // 400 KB

    char* w = (char*)d_ws;
    float* bufA       = (float*)(w);                    w += embBytes;
    float* bufB       = (float*)(w);                    w += embBytes;   // doubles as tmp
    float* acc        = (float*)(w);                    w += embBytes;
    int2*  sorted     = (int2*)(w);                     w += edgeBytes;
    int*   deg        = (int*)(w);                      w += nodeBytes;
    int*   partial    = (int*)(w);                      w += nodeBytes;
    int*   rowStart   = (int*)(w);                      w += nodeBytes;
    int*   blockSums  = (int*)(w);                      w += 512 * sizeof(int);
    int*   blockScan  = (int*)(w);                      w += 512 * sizeof(int);
    int*   bucketCursor = (int*)(w);                    w += NBUCK * sizeof(int);

    unsigned long long* tmp = (unsigned long long*)bufB; // dead before first pull write

    const int vecTotal   = N_NODES * (EMB_DIM / 4);
    const int initBlocks = (vecTotal + 255) / 256;
    const int edgeBlocks = (NNZ + 255) / 256;

    init_emb_kernel<<<initBlocks, 256, 0, stream>>>(user_emb, item_emb, bufA, acc);

    // CSR offsets
    hipMemsetAsync(deg, 0, nodeBytes, stream);
    hist_kernel<<<edgeBlocks, 256, 0, stream>>>(edge_dst, deg);
    scan1_kernel<<<NB, SCAN_BS, 0, stream>>>(deg, partial, blockSums);
    scan2_kernel<<<1, 512, 0, stream>>>(blockSums, blockScan);
    scan3_kernel<<<(N_NODES + 255) / 256, 256, 0, stream>>>(partial, blockScan, rowStart);
    bucket_init_kernel<<<1, NBUCK, 0, stream>>>(rowStart, bucketCursor);

    // two-level partition sort
    const int partABlocks = (NNZ + TILE_EDGES - 1) / TILE_EDGES;          // 391
    partA_kernel<<<partABlocks, 256, 0, stream>>>(edge_val, edge_src, edge_dst,
                                                  bucketCursor, tmp);
    const int partBBlocks = (N_NODES + (1 << ABITS) - 1) / (1 << ABITS);  // 196
    partB_kernel<<<partBBlocks, 1024, 0, stream>>>(tmp, rowStart, sorted);

    // 3 pull layers, acc fused
    const int pullBlocks = (N_NODES * 64 + 255) / 256;
    for (int layer = 0; layer < N_LAYERS; ++layer) {
        pull_kernel<<<pullBlocks, 256, 0, stream>>>(bufA, bufB, acc, sorted, rowStart, deg,
                                                    layer < N_LAYERS - 1 ? 1 : 0);
        float* tmpswap = bufA; bufA = bufB; bufB = tmpswap;
    }

    const int dotBlocks = (BATCH * 64 + 255) / 256;
    dot_kernel<<<dotBlocks, 256, 0, stream>>>(acc, users, items, out);
}

// Round 5
// 570.947 us; speedup vs baseline: 3.8986x; 1.2544x over previous
//
#include <hip/hip_runtime.h>

#define NUM_USERS 50000
#define NUM_ITEMS 50000
#define N_NODES   100000
#define NNZ       3200000
#define EMB_DIM   64
#define N_LAYERS  3
#define BATCH     16384

#define NBUCK 512
#define ABITS 8                  // bucket = dst >> 8 (256 nodes/bucket, 391 used)
#define NODES_PER_BUCK 256
#define TILE_EDGES 8192
#define NBUCK_BLOCKS ((N_NODES + NODES_PER_BUCK - 1) / NODES_PER_BUCK)   // 391

typedef unsigned long long ull;

// init: bufA = acc = concat(user_emb, item_emb), vectorized float4
__global__ void init_emb_kernel(const float* __restrict__ ue,
                                const float* __restrict__ ie,
                                float* __restrict__ bufA,
                                float* __restrict__ acc) {
    int idx = blockIdx.x * blockDim.x + threadIdx.x;
    const int total = N_NODES * (EMB_DIM / 4);
    if (idx >= total) return;
    const int uoff = NUM_USERS * (EMB_DIM / 4);
    float4 v;
    if (idx < uoff) v = ((const float4*)ue)[idx];
    else            v = ((const float4*)ie)[idx - uoff];
    ((float4*)bufA)[idx] = v;
    ((float4*)acc)[idx]  = v;
}

// coarse 512-bucket histogram of dst>>8 (LDS per tile, one global atomic per bucket)
__global__ void bucket_hist_kernel(const int* __restrict__ ed, int* __restrict__ bucketCnt) {
    __shared__ int h[NBUCK];
    int tid = threadIdx.x;
    int e0 = blockIdx.x * TILE_EDGES;
    for (int i = tid; i < NBUCK; i += 256) h[i] = 0;
    __syncthreads();
    for (int i = tid; i < TILE_EDGES; i += 256) {
        int e = e0 + i;
        if (e < NNZ) atomicAdd(&h[((unsigned)ed[e]) >> ABITS], 1);
    }
    __syncthreads();
    for (int i = tid; i < NBUCK; i += 256) {
        int c = h[i];
        if (c) atomicAdd(&bucketCnt[i], c);
    }
}

// single-block exclusive scan of 512 bucket counts -> bucketStart (+cursor copy)
__global__ void bucket_scan_kernel(const int* __restrict__ bucketCnt,
                                   int* __restrict__ bucketStart,
                                   int* __restrict__ bucketCursor) {
    __shared__ int sm[NBUCK];
    int t = threadIdx.x;          // 512
    int v = bucketCnt[t];
    sm[t] = v;
    __syncthreads();
    for (int o = 1; o < NBUCK; o <<= 1) {
        int add = (t >= o) ? sm[t - o] : 0;
        __syncthreads();
        sm[t] += add;
        __syncthreads();
    }
    int excl = sm[t] - v;
    bucketStart[t]  = excl;
    bucketCursor[t] = excl;
    if (t == NBUCK - 1) bucketStart[NBUCK] = NNZ;
}

// pass A: partition edges into 512 coarse buckets.
// rec = src(17) | dstLocal(8)<<17  in low32;  full val bits in high32.
__global__ void partA_kernel(const float* __restrict__ ev,
                             const int*  __restrict__ es,
                             const int*  __restrict__ ed,
                             int* __restrict__ bucketCursor,
                             ull* __restrict__ tmp) {
    __shared__ int hist[NBUCK];
    __shared__ int base[NBUCK];
    __shared__ int cnt2[NBUCK];
    int tid = threadIdx.x;
    int e0 = blockIdx.x * TILE_EDGES;

    for (int i = tid; i < NBUCK; i += 256) hist[i] = 0;
    __syncthreads();
    for (int i = tid; i < TILE_EDGES; i += 256) {
        int e = e0 + i;
        if (e < NNZ) atomicAdd(&hist[((unsigned)ed[e]) >> ABITS], 1);
    }
    __syncthreads();
    for (int i = tid; i < NBUCK; i += 256) {
        int c = hist[i];
        base[i] = c ? atomicAdd(&bucketCursor[i], c) : 0;
        cnt2[i] = 0;
    }
    __syncthreads();
    for (int i = tid; i < TILE_EDGES; i += 256) {
        int e = e0 + i;
        if (e >= NNZ) continue;
        int dst = ed[e];
        int b = ((unsigned)dst) >> ABITS;
        int pos = base[b] + atomicAdd(&cnt2[b], 1);
        ull rec = (ull)(unsigned)(es[e] | ((dst & (NODES_PER_BUCK - 1)) << 17))
                | ((ull)(unsigned)__float_as_int(ev[e]) << 32);
        tmp[pos] = rec;
    }
}

// pass B: per bucket — node degrees + rowStart via LDS scan, then scatter to CSR.
__global__ void partB_kernel(const ull* __restrict__ tmp,
                             const int* __restrict__ bucketStart,
                             int* __restrict__ rowStart,
                             int* __restrict__ deg,
                             int2* __restrict__ sorted) {
    __shared__ int cnt[NODES_PER_BUCK];
    __shared__ int sc[NODES_PER_BUCK];
    __shared__ int cur[NODES_PER_BUCK];
    int b = blockIdx.x;
    int tid = threadIdx.x;           // 1024
    int nodeLo = b << ABITS;
    int startE = bucketStart[b];
    int endE   = bucketStart[b + 1];

    if (tid < NODES_PER_BUCK) cnt[tid] = 0;
    __syncthreads();
    for (int i = startE + tid; i < endE; i += 1024) {
        ull rec = tmp[i];
        atomicAdd(&cnt[(int)((rec >> 17) & (NODES_PER_BUCK - 1))], 1);
    }
    __syncthreads();
    if (tid < NODES_PER_BUCK) sc[tid] = cnt[tid];
    __syncthreads();
    for (int o = 1; o < NODES_PER_BUCK; o <<= 1) {
        int add = 0;
        if (tid < NODES_PER_BUCK && tid >= o) add = sc[tid - o];
        __syncthreads();
        if (tid < NODES_PER_BUCK) sc[tid] += add;
        __syncthreads();
    }
    if (tid < NODES_PER_BUCK) {
        int node = nodeLo + tid;
        int rs = startE + sc[tid] - cnt[tid];
        cur[tid] = rs;
        if (node < N_NODES) {
            rowStart[node] = rs;
            deg[node] = cnt[tid];
        }
    }
    __syncthreads();
    for (int i = startE + tid; i < endE; i += 1024) {
        ull rec = tmp[i];
        int dl  = (int)((rec >> 17) & (NODES_PER_BUCK - 1));
        int src = (int)(rec & 0x1FFFFULL);
        int pos = atomicAdd(&cur[dl], 1);
        sorted[pos] = make_int2(src, (int)(rec >> 32));
    }
}

// ---- pull: one wave per dst node; lane = (edge-subgroup, dim-quad).
// One dwordx4 gather serves 4 edges -> 16 edges in flight per wave.
__global__ void pull_kernel(const float* __restrict__ A,
                            float* __restrict__ B,
                            float* __restrict__ acc,
                            const int2* __restrict__ sorted,
                            const int* __restrict__ rowStart,
                            const int* __restrict__ deg,
                            int writeB) {
    int t = blockIdx.x * blockDim.x + threadIdx.x;
    int node = t >> 6;
    if (node >= N_NODES) return;
    int lane = t & 63;
    int eg = lane >> 4;      // 0..3 edge subgroup
    int d4 = lane & 15;      // dim quad (4 floats)
    int start = rowStart[node];
    int cnt   = deg[node];   // wave-uniform
    const int2* ep = sorted + start;
    const float4* A4 = (const float4*)A;

    float4 a0 = make_float4(0.f,0.f,0.f,0.f), a1 = a0, a2 = a0, a3 = a0;
    int j = 0;
    while (j + 16 <= cnt) {
        int2 r0 = ep[j + eg], r1 = ep[j + 4 + eg], r2 = ep[j + 8 + eg], r3 = ep[j + 12 + eg];
        float4 g0 = A4[(((long long)r0.x) << 4) + d4];
        float4 g1 = A4[(((long long)r1.x) << 4) + d4];
        float4 g2 = A4[(((long long)r2.x) << 4) + d4];
        float4 g3 = A4[(((long long)r3.x) << 4) + d4];
        float w0 = __int_as_float(r0.y), w1 = __int_as_float(r1.y);
        float w2 = __int_as_float(r2.y), w3 = __int_as_float(r3.y);
        a0.x = fmaf(w0, g0.x, a0.x); a0.y = fmaf(w0, g0.y, a0.y);
        a0.z = fmaf(w0, g0.z, a0.z); a0.w = fmaf(w0, g0.w, a0.w);
        a1.x = fmaf(w1, g1.x, a1.x); a1.y = fmaf(w1, g1.y, a1.y);
        a1.z = fmaf(w1, g1.z, a1.z); a1.w = fmaf(w1, g1.w, a1.w);
        a2.x = fmaf(w2, g2.x, a2.x); a2.y = fmaf(w2, g2.y, a2.y);
        a2.z = fmaf(w2, g2.z, a2.z); a2.w = fmaf(w2, g2.w, a2.w);
        a3.x = fmaf(w3, g3.x, a3.x); a3.y = fmaf(w3, g3.y, a3.y);
        a3.z = fmaf(w3, g3.z, a3.z); a3.w = fmaf(w3, g3.w, a3.w);
        j += 16;
    }
    for (; j < cnt; j += 4) {
        int idx = j + eg;
        int2 e = (idx < cnt) ? ep[idx] : make_int2(0, 0);   // val bits 0 -> w = 0.0f
        float4 g = A4[(((long long)e.x) << 4) + d4];
        float w = __int_as_float(e.y);
        a0.x = fmaf(w, g.x, a0.x); a0.y = fmaf(w, g.y, a0.y);
        a0.z = fmaf(w, g.z, a0.z); a0.w = fmaf(w, g.w, a0.w);
    }
    float4 s;
    s.x = (a0.x + a1.x) + (a2.x + a3.x);
    s.y = (a0.y + a1.y) + (a2.y + a3.y);
    s.z = (a0.z + a1.z) + (a2.z + a3.z);
    s.w = (a0.w + a1.w) + (a2.w + a3.w);
    s.x += __shfl_xor(s.x, 16, 64); s.y += __shfl_xor(s.y, 16, 64);
    s.z += __shfl_xor(s.z, 16, 64); s.w += __shfl_xor(s.w, 16, 64);
    s.x += __shfl_xor(s.x, 32, 64); s.y += __shfl_xor(s.y, 32, 64);
    s.z += __shfl_xor(s.z, 32, 64); s.w += __shfl_xor(s.w, 32, 64);
    if (eg == 0) {
        long long o = ((long long)node << 4) + d4;   // float4 index
        float4* B4 = (float4*)B;
        float4* C4 = (float4*)acc;
        float4 c = C4[o];
        c.x += s.x; c.y += s.y; c.z += s.z; c.w += s.w;
        if (writeB) B4[o] = s;
        C4[o] = c;
    }
}

// one wave per batch element: dot(acc[u], acc[NUM_USERS+i]) / 16
__global__ void dot_kernel(const float* __restrict__ acc,
                           const int* __restrict__ users,
                           const int* __restrict__ items,
                           float* __restrict__ out) {
    int t = blockIdx.x * blockDim.x + threadIdx.x;
    int b = t >> 6;
    int d = t & 63;
    if (b >= BATCH) return;
    int u  = users[b];
    int it = items[b] + NUM_USERS;
    float p = acc[(long long)u * EMB_DIM + d] * acc[(long long)it * EMB_DIM + d];
    #pragma unroll
    for (int off = 32; off >= 1; off >>= 1)
        p += __shfl_down(p, off, 64);
    if (d == 0) out[b] = p * 0.0625f;
}

extern "C" void kernel_launch(void* const* d_in, const int* in_sizes, int n_in,
                              void* d_out, int out_size, void* d_ws, size_t ws_size,
                              hipStream_t stream) {
    const float* user_emb = (const float*)d_in[0];
    const float* item_emb = (const float*)d_in[1];
    const float* edge_val = (const float*)d_in[2];
    const int*   edge_src = (const int*)d_in[3];
    const int*   edge_dst = (const int*)d_in[4];
    const int*   users    = (const int*)d_in[5];
    const int*   items    = (const int*)d_in[6];
    float* out = (float*)d_out;

    const size_t embBytes  = (size_t)N_NODES * EMB_DIM * sizeof(float);  // 25.6 MB
    const size_t edgeBytes = (size_t)NNZ * sizeof(int2);                 // 25.6 MB
    const size_t nodeBytes = (size_t)N_NODES * sizeof(int);              // 400 KB

    char* w = (char*)d_ws;
    float* bufA         = (float*)(w);   w += embBytes;
    float* bufB         = (float*)(w);   w += embBytes;   // doubles as tmp
    float* acc          = (float*)(w);   w += embBytes;
    int2*  sorted       = (int2*)(w);    w += edgeBytes;
    int*   deg          = (int*)(w);     w += nodeBytes;
    int*   rowStart     = (int*)(w);     w += nodeBytes;
    int*   bucketCnt    = (int*)(w);     w += NBUCK * sizeof(int);
    int*   bucketStart  = (int*)(w);     w += (NBUCK + 1) * sizeof(int);
    int*   bucketCursor = (int*)(w);     w += NBUCK * sizeof(int);

    ull* tmp = (ull*)bufB;   // dead before first pull write

    const int vecTotal   = N_NODES * (EMB_DIM / 4);
    const int initBlocks = (vecTotal + 255) / 256;
    const int tileBlocks = (NNZ + TILE_EDGES - 1) / TILE_EDGES;   // 391

    init_emb_kernel<<<initBlocks, 256, 0, stream>>>(user_emb, item_emb, bufA, acc);

    hipMemsetAsync(bucketCnt, 0, NBUCK * sizeof(int), stream);
    bucket_hist_kernel<<<tileBlocks, 256, 0, stream>>>(edge_dst, bucketCnt);
    bucket_scan_kernel<<<1, NBUCK, 0, stream>>>(bucketCnt, bucketStart, bucketCursor);
    partA_kernel<<<tileBlocks, 256, 0, stream>>>(edge_val, edge_src, edge_dst,
                                                 bucketCursor, tmp);
    partB_kernel<<<NBUCK_BLOCKS, 1024, 0, stream>>>(tmp, bucketStart, rowStart, deg, sorted);

    const int pullBlocks = (N_NODES * 64 + 255) / 256;
    for (int layer = 0; layer < N_LAYERS; ++layer) {
        pull_kernel<<<pullBlocks, 256, 0, stream>>>(bufA, bufB, acc, sorted, rowStart, deg,
                                                    layer < N_LAYERS - 1 ? 1 : 0);
        float* tmpswap = bufA; bufA = bufB; bufB = tmpswap;
    }

    const int dotBlocks = (BATCH * 64 + 255) / 256;
    dot_kernel<<<dotBlocks, 256, 0, stream>>>(acc, users, items, out);
}